// Round 14
// baseline (201.686 us; speedup 1.0000x reference)
//
#include <hip/hip_runtime.h>
#include <hip/hip_bf16.h>

typedef unsigned short u16;
typedef unsigned int   u32;
typedef unsigned long long u64;
typedef __attribute__((ext_vector_type(8))) short short8;   // 8 bf16 (4 VGPRs)
typedef __attribute__((ext_vector_type(4))) float float4v;  // 4 fp32 acc

#define N 8192
#define D 128
#define C 1000
#define TILE 128
#define LDT 136        // padded LDS row stride (272B -> 2-way aliasing, free)
#define NW64 (N / 64)  // 128 packed words per class row
#define JQ 8           // 64-wide j-tiles per block
#define LOG2E 1.44269504088896340736f

// ---------------------------------------------------------------------------
// Kernel A: per-row L2 normalize (write bf16) + exact fp32 proxy term p_i.
// Also zeroes den/num. One wave per row.
// ---------------------------------------------------------------------------
__global__ void norm_kernel(const float* __restrict__ x, const float* __restrict__ pr,
                            u16* __restrict__ xnb, float* __restrict__ p_out,
                            float* __restrict__ den, float* __restrict__ num,
                            const float* __restrict__ tp, const float* __restrict__ mp) {
    const int wave = threadIdx.x >> 6;
    const int lane = threadIdx.x & 63;
    const int row  = blockIdx.x * 4 + wave;

    const float2* xr  = (const float2*)(x  + (size_t)row * D);
    const float2* prr = (const float2*)(pr + (size_t)row * D);
    float2 xv = xr[lane];
    float2 pv = prr[lane];

    float sx  = xv.x * xv.x + xv.y * xv.y;
    float sp  = pv.x * pv.x + pv.y * pv.y;
    float sxp = xv.x * pv.x + xv.y * pv.y;
    #pragma unroll
    for (int off = 32; off; off >>= 1) {
        sx  += __shfl_xor(sx,  off);
        sp  += __shfl_xor(sp,  off);
        sxp += __shfl_xor(sxp, off);
    }
    float nx = fmaxf(sqrtf(sx), 1e-8f);
    float np = fmaxf(sqrtf(sp), 1e-8f);
    float inv = 1.0f / nx;

    __hip_bfloat16 b0 = __float2bfloat16(xv.x * inv);
    __hip_bfloat16 b1 = __float2bfloat16(xv.y * inv);
    ((__hip_bfloat162*)xnb)[(size_t)row * 64 + lane] = __halves2bfloat162(b0, b1);

    if (lane == 0) {
        float T = tp[0], M = mp[0];
        p_out[row] = __expf((sxp / (nx * np) - M) / T);
        den[row] = 0.0f;
        num[row] = 0.0f;
    }
}

// ---------------------------------------------------------------------------
// Kernel B: coalesced bit-pack of negative_mask [N, C] -> packed[l][w] bit j.
// ---------------------------------------------------------------------------
__global__ void pack_kernel(const float* __restrict__ nm, u64* __restrict__ packed) {
    __shared__ u32 Ls[64 * 65];
    const int lane = threadIdx.x & 63;
    const int wv   = threadIdx.x >> 6;
    const int jt   = blockIdx.x;
    const int lt   = blockIdx.y;
    const int j0   = jt * 64;
    const int l    = lt * 64 + lane;
    const bool lv  = l < C;

    #pragma unroll
    for (int rr = 0; rr < 16; rr++) {
        const int r = wv * 16 + rr;
        float v = lv ? nm[(size_t)(j0 + r) * C + l] : 0.0f;
        Ls[r * 65 + lane] = (v > 0.5f) ? 1u : 0u;
    }
    __syncthreads();
    #pragma unroll
    for (int cc = 0; cc < 16; cc++) {
        const int c = wv * 16 + cc;
        u64 m = __ballot(Ls[lane * 65 + c] != 0u);
        if (lane == 0 && (lt * 64 + c) < C)
            packed[(size_t)(lt * 64 + c) * NW64 + jt] = m;
    }
}

// ---------------------------------------------------------------------------
// Kernel C: fused sim-GEMM + exp + mask + per-row partial sums.
// R6 structure at the feasible register point:
//   - A tile (128x128) staged in LDS ONCE (one barrier), 34816 B.
//   - Wave tile 32(i) x 64(j): acc = 32 AGPR; live arch set ~81 regs.
//   - __launch_bounds__(256,3): allocator grants arch=84 >= 81 -> NO spill
//     (R6's (256,4)=64-arch spilled ~4 regs/q -> 36 MB; R13's A-in-regs
//     needed 114 > 84). 3 waves/SIMD, 3 blocks/CU, 12 waves/CU.
//   - B per-kk from global (L1-shared by the 4 waves); latency covered by
//     1.5x TLP instead of R8's rotation (which costs +16 live regs).
//   - Mask words preloaded before MFMA (hide under matrix pipe).
// grid = (64 i-tiles, 16 j-splits of 8 64-wide tiles) = 1024 blocks.
// ---------------------------------------------------------------------------
template <bool DIAG>
__device__ __forceinline__ void epilogue(const float4v acc[2][4], const u64 wq[2][4],
                                         float dacc[2][4], float nacc[2][4],
                                         int kq, int m0, int rb, int jb,
                                         float kA2, float kB2) {
    #pragma unroll
    for (int tm = 0; tm < 2; tm++) {
        #pragma unroll
        for (int r = 0; r < 4; r++) {
            const u64 ws = wq[tm][r] >> m0;
            const u32 wlo = (u32)ws, whi = (u32)(ws >> 32);
            const int gi = rb + tm * 16 + kq * 4 + r;
            #pragma unroll
            for (int tn = 0; tn < 4; tn++) {
                float e = __builtin_amdgcn_exp2f(fmaf(acc[tm][tn][r], kA2, kB2));
                if (DIAG) {
                    const int gj = jb + tn * 16 + m0;
                    if (gi == gj) e = 0.0f;
                }
                dacc[tm][r] += e;
                const u32 bit = ((tn < 2) ? (wlo >> (tn * 16)) : (whi >> ((tn - 2) * 16))) & 1u;
                nacc[tm][r] = fmaf((float)bit, e, nacc[tm][r]);
            }
        }
    }
}

__global__ __launch_bounds__(256, 3)
void cc_main(const u16* __restrict__ xnb, const int* __restrict__ labels,
             const u64* __restrict__ packed,
             float* __restrict__ den, float* __restrict__ num,
             const float* __restrict__ tp, const float* __restrict__ mp) {
    __shared__ u16 As[TILE * LDT];   // 34816 B

    const int tid  = threadIdx.x;
    const int lane = tid & 63;
    const int wv   = tid >> 6;       // wave's 32-row strip within the 128-row tile
    const int m0   = lane & 15;
    const int kq   = lane >> 4;      // 0..3
    const int ibase = blockIdx.x * TILE;
    const int rb    = ibase + wv * 32;
    const int jw0   = blockIdx.y * JQ;

    const float T = tp[0];
    const float M = mp[0];
    const float kA2 = LOG2E / T;
    const float kB2 = -M * LOG2E / T;

    // stage A tile (128 x 128 bf16), each thread 128 B
    {
        const int r = tid >> 1, h = tid & 1;
        const uint4* src = (const uint4*)(xnb + (size_t)(ibase + r) * D + h * 64);
        uint4* dst = (uint4*)(As + r * LDT + h * 64);
        #pragma unroll
        for (int qq = 0; qq < 8; qq++) dst[qq] = src[qq];
    }

    // packed-row base offsets for the 8 epilogue rows this lane owns
    u32 offs[2][4];
    #pragma unroll
    for (int tm = 0; tm < 2; tm++)
        #pragma unroll
        for (int r = 0; r < 4; r++)
            offs[tm][r] = (u32)labels[rb + tm * 16 + kq * 4 + r] * NW64 + jw0;

    __syncthreads();

    float dacc[2][4] = {};
    float nacc[2][4] = {};

    const u16* Abase = As + (wv * 32 + m0) * LDT + kq * 8;

    for (int q = 0; q < JQ; q++) {
        const int jb = (jw0 + q) * 64;
        const u16* Bp = xnb + (size_t)(jb + m0) * D + kq * 8;

        // mask words for this q-tile (broadcast u64 gathers) -- issue early
        u64 wq[2][4];
        #pragma unroll
        for (int tm = 0; tm < 2; tm++)
            #pragma unroll
            for (int r = 0; r < 4; r++)
                wq[tm][r] = packed[offs[tm][r] + q];

        float4v acc[2][4];
        #pragma unroll
        for (int a = 0; a < 2; a++)
            #pragma unroll
            for (int b = 0; b < 4; b++)
                acc[a][b] = (float4v){0.f, 0.f, 0.f, 0.f};

        #pragma unroll
        for (int kk = 0; kk < 4; kk++) {
            short8 b_f[4];
            #pragma unroll
            for (int tn = 0; tn < 4; tn++)
                b_f[tn] = *(const short8*)(Bp + tn * (16 * D) + kk * 32);
            short8 a_f[2];
            #pragma unroll
            for (int tm = 0; tm < 2; tm++)
                a_f[tm] = *(const short8*)(Abase + tm * (16 * LDT) + kk * 32);
            #pragma unroll
            for (int tm = 0; tm < 2; tm++)
                #pragma unroll
                for (int tn = 0; tn < 4; tn++)
                    acc[tm][tn] = __builtin_amdgcn_mfma_f32_16x16x32_bf16(
                        a_f[tm], b_f[tn], acc[tm][tn], 0, 0, 0);
        }

        // diagonal only when this wave's 32 rows fall inside this 64-col tile
        if ((rb >> 6) == (jw0 + q))
            epilogue<true >(acc, wq, dacc, nacc, kq, m0, rb, jb, kA2, kB2);
        else
            epilogue<false>(acc, wq, dacc, nacc, kq, m0, rb, jb, kA2, kB2);
    }

    // reduce across the 16 column-lanes, then atomics
    #pragma unroll
    for (int tm = 0; tm < 2; tm++) {
        #pragma unroll
        for (int r = 0; r < 4; r++) {
            float d = dacc[tm][r], n = nacc[tm][r];
            #pragma unroll
            for (int off = 1; off < 16; off <<= 1) {
                d += __shfl_xor(d, off);
                n += __shfl_xor(n, off);
            }
            if (m0 == 0) {
                const int gi = rb + tm * 16 + kq * 4 + r;
                atomicAdd(&den[gi], d);
                atomicAdd(&num[gi], n);
            }
        }
    }
}

// ---------------------------------------------------------------------------
// Kernel D: final loss = mean_i -log(T * (p_i + num_i) / (p_i + den_i))
// ---------------------------------------------------------------------------
__global__ void loss_kernel(const float* __restrict__ p, const float* __restrict__ den,
                            const float* __restrict__ num, float* __restrict__ out,
                            const float* __restrict__ tp) {
    __shared__ float red[16];
    const float T = tp[0];
    float s = 0.0f;
    #pragma unroll
    for (int t = 0; t < N / 1024; t++) {
        const int i = t * 1024 + threadIdx.x;
        float pi = p[i];
        s += -__logf(T * (pi + num[i]) / (pi + den[i]));
    }
    #pragma unroll
    for (int off = 32; off; off >>= 1) s += __shfl_xor(s, off);
    const int lane = threadIdx.x & 63, wv = threadIdx.x >> 6;
    if (lane == 0) red[wv] = s;
    __syncthreads();
    if (wv == 0) {
        float t = (lane < 16) ? red[lane] : 0.0f;
        #pragma unroll
        for (int off = 8; off; off >>= 1) t += __shfl_xor(t, off);
        if (lane == 0) out[0] = t / (float)N;
    }
}

// ---------------------------------------------------------------------------
extern "C" void kernel_launch(void* const* d_in, const int* in_sizes, int n_in,
                              void* d_out, int out_size, void* d_ws, size_t ws_size,
                              hipStream_t stream) {
    (void)in_sizes; (void)n_in; (void)out_size; (void)ws_size;
    const float* inst   = (const float*)d_in[0];
    const float* proxy  = (const float*)d_in[1];
    const float* nm     = (const float*)d_in[2];
    const int*   labels = (const int*)d_in[3];
    const float* temp   = (const float*)d_in[4];
    const float* marg   = (const float*)d_in[5];
    float* out = (float*)d_out;

    char* ws = (char*)d_ws;
    u16*   xnb    = (u16*)ws;                         // N*D*2      = 2,097,152 B
    float* p_arr  = (float*)(ws + 2097152);           // N*4        = 32,768 B
    u64*   packed = (u64*)(ws + 2129920);             // C*128*8    = 1,024,000 B
    float* den    = (float*)(ws + 3153920);           // N*4
    float* num    = (float*)(ws + 3186688);           // N*4

    pack_kernel<<<dim3(N / 64, 16), 256, 0, stream>>>(nm, packed);
    norm_kernel<<<N / 4, 256, 0, stream>>>(inst, proxy, xnb, p_arr, den, num, temp, marg);
    cc_main<<<dim3(N / TILE, 16), 256, 0, stream>>>(xnb, labels, packed, den, num, temp, marg);
    loss_kernel<<<1, 1024, 0, stream>>>(p_arr, den, num, out, temp);
}

// Round 15
// 138.723 us; speedup vs baseline: 1.4539x; 1.4539x over previous
//
#include <hip/hip_runtime.h>
#include <hip/hip_bf16.h>

typedef unsigned short u16;
typedef unsigned int   u32;
typedef unsigned long long u64;
typedef __attribute__((ext_vector_type(8))) short short8;   // 8 bf16 (4 VGPRs)
typedef __attribute__((ext_vector_type(4))) float float4v;  // 4 fp32 acc

#define N 8192
#define D 128
#define C 1000
#define TILE 128
#define LDT 136        // padded LDS row stride in bf16
#define NW64 (N / 64)  // 128 packed words per class row
#define JQ 8           // j-tiles per block
#define JW (JQ * 2)    // mask words per row per block
#define LOG2E 1.44269504088896340736f

// ---------------------------------------------------------------------------
// Kernel A: per-row L2 normalize (write bf16) + exact fp32 proxy term p_i.
// Also zeroes den/num. One wave per row.
// ---------------------------------------------------------------------------
__global__ void norm_kernel(const float* __restrict__ x, const float* __restrict__ pr,
                            u16* __restrict__ xnb, float* __restrict__ p_out,
                            float* __restrict__ den, float* __restrict__ num,
                            const float* __restrict__ tp, const float* __restrict__ mp) {
    const int wave = threadIdx.x >> 6;
    const int lane = threadIdx.x & 63;
    const int row  = blockIdx.x * 4 + wave;

    const float2* xr  = (const float2*)(x  + (size_t)row * D);
    const float2* prr = (const float2*)(pr + (size_t)row * D);
    float2 xv = xr[lane];
    float2 pv = prr[lane];

    float sx  = xv.x * xv.x + xv.y * xv.y;
    float sp  = pv.x * pv.x + pv.y * pv.y;
    float sxp = xv.x * pv.x + xv.y * pv.y;
    #pragma unroll
    for (int off = 32; off; off >>= 1) {
        sx  += __shfl_xor(sx,  off);
        sp  += __shfl_xor(sp,  off);
        sxp += __shfl_xor(sxp, off);
    }
    float nx = fmaxf(sqrtf(sx), 1e-8f);
    float np = fmaxf(sqrtf(sp), 1e-8f);
    float inv = 1.0f / nx;

    __hip_bfloat16 b0 = __float2bfloat16(xv.x * inv);
    __hip_bfloat16 b1 = __float2bfloat16(xv.y * inv);
    ((__hip_bfloat162*)xnb)[(size_t)row * 64 + lane] = __halves2bfloat162(b0, b1);

    if (lane == 0) {
        float T = tp[0], M = mp[0];
        p_out[row] = __expf((sxp / (nx * np) - M) / T);
        den[row] = 0.0f;
        num[row] = 0.0f;
    }
}

// ---------------------------------------------------------------------------
// Kernel B: coalesced bit-pack of negative_mask [N, C] -> packed[l][w] bit j.
// ---------------------------------------------------------------------------
__global__ void pack_kernel(const float* __restrict__ nm, u64* __restrict__ packed) {
    __shared__ u32 Ls[64 * 65];
    const int lane = threadIdx.x & 63;
    const int wv   = threadIdx.x >> 6;
    const int jt   = blockIdx.x;
    const int lt   = blockIdx.y;
    const int j0   = jt * 64;
    const int l    = lt * 64 + lane;
    const bool lv  = l < C;

    #pragma unroll
    for (int rr = 0; rr < 16; rr++) {
        const int r = wv * 16 + rr;
        float v = lv ? nm[(size_t)(j0 + r) * C + l] : 0.0f;
        Ls[r * 65 + lane] = (v > 0.5f) ? 1u : 0u;
    }
    __syncthreads();
    #pragma unroll
    for (int cc = 0; cc < 16; cc++) {
        const int c = wv * 16 + cc;
        u64 m = __ballot(Ls[lane * 65 + c] != 0u);
        if (lane == 0 && (lt * 64 + c) < C)
            packed[(size_t)(lt * 64 + c) * NW64 + jt] = m;
    }
}

// ---------------------------------------------------------------------------
// Kernel C: fused sim-GEMM + exp + mask + per-row partial sums.
// BEST-KNOWN CONFIG (R11): A+Ms staged once (one barrier), 64x64 wave tile
// split into two 32-col halves with separate 32-AGPR accumulators (ping-pong:
// each epilogue-half overlaps the other half's just-issued MFMA block), B
// depth-1 reload rotation (each B load in flight ~one epilogue >= L2 latency),
// (256,2) -> no spill (2 waves/SIMD is the only spill-free point: 6 attempts
// at >=3 waves all hit the unified-file 50/50 split cliff, arch<=84 < ~90
// live set). grid = (64 i-tiles, 8 j-splits of 8 tiles) = 512 blocks (2/CU).
// ---------------------------------------------------------------------------
template <bool RELOAD>
__device__ __forceinline__ void mfma_half(float4v acc[4][2], const u16* __restrict__ Abase,
                                          short8 bc[4][2], const u16* __restrict__ Bnext) {
    #pragma unroll
    for (int a = 0; a < 4; a++)
        #pragma unroll
        for (int b = 0; b < 2; b++)
            acc[a][b] = (float4v){0.f, 0.f, 0.f, 0.f};
    #pragma unroll
    for (int kk = 0; kk < 4; kk++) {
        short8 a_f[4];
        #pragma unroll
        for (int tm = 0; tm < 4; tm++)
            a_f[tm] = *(const short8*)(Abase + tm * (16 * LDT) + kk * 32);
        #pragma unroll
        for (int tm = 0; tm < 4; tm++)
            #pragma unroll
            for (int tn = 0; tn < 2; tn++)
                acc[tm][tn] = __builtin_amdgcn_mfma_f32_16x16x32_bf16(
                    a_f[tm], bc[kk][tn], acc[tm][tn], 0, 0, 0);
        if (RELOAD) {
            #pragma unroll
            for (int tn = 0; tn < 2; tn++)
                bc[kk][tn] = *(const short8*)(Bnext + tn * (16 * D) + kk * 32);
        }
    }
}

template <bool DIAG, int H>
__device__ __forceinline__ void epi_half(const float4v acc[4][2], const u64* __restrict__ Ms,
                                         float dacc[4][4], float nacc[4][4],
                                         int wr, int wc, int kq, int m0,
                                         int ibase, int jbase, int q,
                                         float kA2, float kB2) {
    #pragma unroll
    for (int tm = 0; tm < 4; tm++) {
        #pragma unroll
        for (int r = 0; r < 4; r++) {
            const int lrow = wr * 64 + tm * 16 + kq * 4 + r;
            const u64 ws = Ms[lrow * JW + q * 2 + wc] >> m0;
            const int gi = ibase + lrow;
            #pragma unroll
            for (int tn = 0; tn < 2; tn++) {
                float e = __builtin_amdgcn_exp2f(fmaf(acc[tm][tn][r], kA2, kB2));
                if (DIAG) {
                    const int gj = jbase + wc * 64 + (H * 2 + tn) * 16 + m0;
                    if (gi == gj) e = 0.0f;
                }
                dacc[tm][r] += e;
                const u32 bit = (u32)(ws >> ((H * 2 + tn) * 16)) & 1u;
                nacc[tm][r] = fmaf((float)bit, e, nacc[tm][r]);
            }
        }
    }
}

__global__ __launch_bounds__(256, 2)
void cc_main(const u16* __restrict__ xnb, const int* __restrict__ labels,
             const u64* __restrict__ packed,
             float* __restrict__ den, float* __restrict__ num,
             const float* __restrict__ tp, const float* __restrict__ mp) {
    __shared__ u16 As[TILE * LDT];    // 34816 B
    __shared__ u64 Ms[TILE * JW];     // 16384 B

    const int tid  = threadIdx.x;
    const int lane = tid & 63;
    const int wv   = tid >> 6;
    const int wr   = wv >> 1;
    const int wc   = wv & 1;
    const int m0   = lane & 15;
    const int kq   = lane >> 4;
    const int ibase  = blockIdx.x * TILE;
    const int jsplit = blockIdx.y;
    const int jt0    = jsplit * JQ;

    const float T = tp[0];
    const float M = mp[0];
    const float kA2 = LOG2E / T;
    const float kB2 = -M * LOG2E / T;

    // stage A tile (128 x 128 bf16), each thread 128 B
    {
        const int r = tid >> 1, h = tid & 1;
        const uint4* src = (const uint4*)(xnb + (size_t)(ibase + r) * D + h * 64);
        uint4* dst = (uint4*)(As + r * LDT + h * 64);
        #pragma unroll
        for (int qq = 0; qq < 8; qq++) dst[qq] = src[qq];
    }
    // stage mask words: 128 rows x 16 words for this j-split
    #pragma unroll
    for (int t = 0; t < 8; t++) {
        const int idx = t * 256 + tid;
        const int row = idx >> 4, h = idx & 15;
        const int lab = labels[ibase + row];
        Ms[idx] = packed[(size_t)lab * NW64 + jt0 * 2 + h];
    }
    __syncthreads();

    float dacc[4][4] = {};
    float nacc[4][4] = {};

    const u16* Abase = As + (wr * 64 + m0) * LDT + kq * 8;
    const u16* Blane = xnb + (size_t)(wc * 64 + m0) * D + kq * 8;

    float4v accA[4][2], accB[4][2];
    short8 bc[4][2];

    // prologue: load B(q=0, half0); mfma accA=(0,h0) while reloading bc<-(0,h1)
    {
        const u16* B0 = Blane + (size_t)(jt0 * TILE) * D;
        #pragma unroll
        for (int kk = 0; kk < 4; kk++)
            #pragma unroll
            for (int tn = 0; tn < 2; tn++)
                bc[kk][tn] = *(const short8*)(B0 + tn * (16 * D) + kk * 32);
        mfma_half<true>(accA, Abase, bc, B0 + 32 * D);
    }

    for (int q = 0; q < JQ; q++) {
        const int jt = jt0 + q;
        const int jbase = jt * TILE;
        const u16* Bn = Blane + (size_t)(jbase + TILE) * D;   // next tile base
        const bool diag = (jt == blockIdx.x);

        // mfma accB=(q,h1); reload bc<-(q+1,h0)   [overlaps epi(accA,q,h0)]
        if (q < JQ - 1) mfma_half<true >(accB, Abase, bc, Bn);
        else            mfma_half<false>(accB, Abase, bc, Bn);

        if (diag) epi_half<true , 0>(accA, Ms, dacc, nacc, wr, wc, kq, m0, ibase, jbase, q, kA2, kB2);
        else      epi_half<false, 0>(accA, Ms, dacc, nacc, wr, wc, kq, m0, ibase, jbase, q, kA2, kB2);

        // mfma accA=(q+1,h0); reload bc<-(q+1,h1) [overlaps epi(accB,q,h1)]
        if (q < JQ - 1) mfma_half<true>(accA, Abase, bc, Bn + 32 * D);

        if (diag) epi_half<true , 1>(accB, Ms, dacc, nacc, wr, wc, kq, m0, ibase, jbase, q, kA2, kB2);
        else      epi_half<false, 1>(accB, Ms, dacc, nacc, wr, wc, kq, m0, ibase, jbase, q, kA2, kB2);
    }

    // reduce across the 16 column-lanes, then atomics
    #pragma unroll
    for (int tm = 0; tm < 4; tm++) {
        #pragma unroll
        for (int r = 0; r < 4; r++) {
            float d = dacc[tm][r], n = nacc[tm][r];
            #pragma unroll
            for (int off = 1; off < 16; off <<= 1) {
                d += __shfl_xor(d, off);
                n += __shfl_xor(n, off);
            }
            if (m0 == 0) {
                const int gi = ibase + wr * 64 + tm * 16 + kq * 4 + r;
                atomicAdd(&den[gi], d);
                atomicAdd(&num[gi], n);
            }
        }
    }
}

// ---------------------------------------------------------------------------
// Kernel D: final loss = mean_i -log(T * (p_i + num_i) / (p_i + den_i))
// ---------------------------------------------------------------------------
__global__ void loss_kernel(const float* __restrict__ p, const float* __restrict__ den,
                            const float* __restrict__ num, float* __restrict__ out,
                            const float* __restrict__ tp) {
    __shared__ float red[16];
    const float T = tp[0];
    float s = 0.0f;
    #pragma unroll
    for (int t = 0; t < N / 1024; t++) {
        const int i = t * 1024 + threadIdx.x;
        float pi = p[i];
        s += -__logf(T * (pi + num[i]) / (pi + den[i]));
    }
    #pragma unroll
    for (int off = 32; off; off >>= 1) s += __shfl_xor(s, off);
    const int lane = threadIdx.x & 63, wv = threadIdx.x >> 6;
    if (lane == 0) red[wv] = s;
    __syncthreads();
    if (wv == 0) {
        float t = (lane < 16) ? red[lane] : 0.0f;
        #pragma unroll
        for (int off = 8; off; off >>= 1) t += __shfl_xor(t, off);
        if (lane == 0) out[0] = t / (float)N;
    }
}

// ---------------------------------------------------------------------------
extern "C" void kernel_launch(void* const* d_in, const int* in_sizes, int n_in,
                              void* d_out, int out_size, void* d_ws, size_t ws_size,
                              hipStream_t stream) {
    (void)in_sizes; (void)n_in; (void)out_size; (void)ws_size;
    const float* inst   = (const float*)d_in[0];
    const float* proxy  = (const float*)d_in[1];
    const float* nm     = (const float*)d_in[2];
    const int*   labels = (const int*)d_in[3];
    const float* temp   = (const float*)d_in[4];
    const float* marg   = (const float*)d_in[5];
    float* out = (float*)d_out;

    char* ws = (char*)d_ws;
    u16*   xnb    = (u16*)ws;                         // N*D*2      = 2,097,152 B
    float* p_arr  = (float*)(ws + 2097152);           // N*4        = 32,768 B
    u64*   packed = (u64*)(ws + 2129920);             // C*128*8    = 1,024,000 B
    float* den    = (float*)(ws + 3153920);           // N*4
    float* num    = (float*)(ws + 3186688);           // N*4

    pack_kernel<<<dim3(N / 64, 16), 256, 0, stream>>>(nm, packed);
    norm_kernel<<<N / 4, 256, 0, stream>>>(inst, proxy, xnb, p_arr, den, num, temp, marg);
    cc_main<<<dim3(N / TILE, 8), 256, 0, stream>>>(xnb, labels, packed, den, num, temp, marg);
    loss_kernel<<<1, 1024, 0, stream>>>(p_arr, den, num, out, temp);
}

// Round 16
// 137.471 us; speedup vs baseline: 1.4671x; 1.0091x over previous
//
#include <hip/hip_runtime.h>
#include <hip/hip_bf16.h>

typedef unsigned short u16;
typedef unsigned int   u32;
typedef unsigned long long u64;
typedef __attribute__((ext_vector_type(8))) short short8;   // 8 bf16 (4 VGPRs)
typedef __attribute__((ext_vector_type(4))) float float4v;  // 4 fp32 acc

#define N 8192
#define D 128
#define C 1000
#define TILE 128
#define LDT 136        // padded LDS row stride in bf16
#define NW64 (N / 64)  // 128 packed words per class row
#define JQ 8           // j-tiles per block
#define JW 16          // mask words per row per block (used)
#define MSP 17         // padded Ms row stride in u64 (136 B -> kq groups hit distinct banks)
#define LOG2E 1.44269504088896340736f

// ---------------------------------------------------------------------------
// Kernel A: per-row L2 normalize (write bf16) + exact fp32 proxy term p_i.
// Also zeroes den/num. One wave per row.
// ---------------------------------------------------------------------------
__global__ void norm_kernel(const float* __restrict__ x, const float* __restrict__ pr,
                            u16* __restrict__ xnb, float* __restrict__ p_out,
                            float* __restrict__ den, float* __restrict__ num,
                            const float* __restrict__ tp, const float* __restrict__ mp) {
    const int wave = threadIdx.x >> 6;
    const int lane = threadIdx.x & 63;
    const int row  = blockIdx.x * 4 + wave;

    const float2* xr  = (const float2*)(x  + (size_t)row * D);
    const float2* prr = (const float2*)(pr + (size_t)row * D);
    float2 xv = xr[lane];
    float2 pv = prr[lane];

    float sx  = xv.x * xv.x + xv.y * xv.y;
    float sp  = pv.x * pv.x + pv.y * pv.y;
    float sxp = xv.x * pv.x + xv.y * pv.y;
    #pragma unroll
    for (int off = 32; off; off >>= 1) {
        sx  += __shfl_xor(sx,  off);
        sp  += __shfl_xor(sp,  off);
        sxp += __shfl_xor(sxp, off);
    }
    float nx = fmaxf(sqrtf(sx), 1e-8f);
    float np = fmaxf(sqrtf(sp), 1e-8f);
    float inv = 1.0f / nx;

    __hip_bfloat16 b0 = __float2bfloat16(xv.x * inv);
    __hip_bfloat16 b1 = __float2bfloat16(xv.y * inv);
    ((__hip_bfloat162*)xnb)[(size_t)row * 64 + lane] = __halves2bfloat162(b0, b1);

    if (lane == 0) {
        float T = tp[0], M = mp[0];
        p_out[row] = __expf((sxp / (nx * np) - M) / T);
        den[row] = 0.0f;
        num[row] = 0.0f;
    }
}

// ---------------------------------------------------------------------------
// Kernel B: coalesced bit-pack of negative_mask [N, C] -> packed[l][w] bit j.
// ---------------------------------------------------------------------------
__global__ void pack_kernel(const float* __restrict__ nm, u64* __restrict__ packed) {
    __shared__ u32 Ls[64 * 65];
    const int lane = threadIdx.x & 63;
    const int wv   = threadIdx.x >> 6;
    const int jt   = blockIdx.x;
    const int lt   = blockIdx.y;
    const int j0   = jt * 64;
    const int l    = lt * 64 + lane;
    const bool lv  = l < C;

    #pragma unroll
    for (int rr = 0; rr < 16; rr++) {
        const int r = wv * 16 + rr;
        float v = lv ? nm[(size_t)(j0 + r) * C + l] : 0.0f;
        Ls[r * 65 + lane] = (v > 0.5f) ? 1u : 0u;
    }
    __syncthreads();
    #pragma unroll
    for (int cc = 0; cc < 16; cc++) {
        const int c = wv * 16 + cc;
        u64 m = __ballot(Ls[lane * 65 + c] != 0u);
        if (lane == 0 && (lt * 64 + c) < C)
            packed[(size_t)(lt * 64 + c) * NW64 + jt] = m;
    }
}

// ---------------------------------------------------------------------------
// Kernel C: fused sim-GEMM + exp + mask + per-row partial sums.
// R11 config (best known) + padded Ms stride (17 u64/row): the 4 kq lane
// groups of each epilogue Ms read previously hit the SAME bank (row stride
// was exactly 32 banks -> 4-way conflict on every read, 2.24M conflict
// cycles). Stride 17 -> banks 2*base+8*kq+2*off, all distinct -> conflict
// free. Everything else identical: A+Ms staged once (one barrier), 64x64
// wave tile as two 32-col ping-pong halves (each epilogue overlaps the other
// half's MFMA block), B depth-1 reload rotation, (256,2) no-spill point.
// grid = (64 i-tiles, 8 j-splits of 8 tiles) = 512 blocks (2/CU).
// ---------------------------------------------------------------------------
template <bool RELOAD>
__device__ __forceinline__ void mfma_half(float4v acc[4][2], const u16* __restrict__ Abase,
                                          short8 bc[4][2], const u16* __restrict__ Bnext) {
    #pragma unroll
    for (int a = 0; a < 4; a++)
        #pragma unroll
        for (int b = 0; b < 2; b++)
            acc[a][b] = (float4v){0.f, 0.f, 0.f, 0.f};
    #pragma unroll
    for (int kk = 0; kk < 4; kk++) {
        short8 a_f[4];
        #pragma unroll
        for (int tm = 0; tm < 4; tm++)
            a_f[tm] = *(const short8*)(Abase + tm * (16 * LDT) + kk * 32);
        #pragma unroll
        for (int tm = 0; tm < 4; tm++)
            #pragma unroll
            for (int tn = 0; tn < 2; tn++)
                acc[tm][tn] = __builtin_amdgcn_mfma_f32_16x16x32_bf16(
                    a_f[tm], bc[kk][tn], acc[tm][tn], 0, 0, 0);
        if (RELOAD) {
            #pragma unroll
            for (int tn = 0; tn < 2; tn++)
                bc[kk][tn] = *(const short8*)(Bnext + tn * (16 * D) + kk * 32);
        }
    }
}

template <bool DIAG, int H>
__device__ __forceinline__ void epi_half(const float4v acc[4][2], const u64* __restrict__ Ms,
                                         float dacc[4][4], float nacc[4][4],
                                         int wr, int wc, int kq, int m0,
                                         int ibase, int jbase, int q,
                                         float kA2, float kB2) {
    #pragma unroll
    for (int tm = 0; tm < 4; tm++) {
        #pragma unroll
        for (int r = 0; r < 4; r++) {
            const int lrow = wr * 64 + tm * 16 + kq * 4 + r;
            const u64 ws = Ms[lrow * MSP + q * 2 + wc] >> m0;
            const int gi = ibase + lrow;
            #pragma unroll
            for (int tn = 0; tn < 2; tn++) {
                float e = __builtin_amdgcn_exp2f(fmaf(acc[tm][tn][r], kA2, kB2));
                if (DIAG) {
                    const int gj = jbase + wc * 64 + (H * 2 + tn) * 16 + m0;
                    if (gi == gj) e = 0.0f;
                }
                dacc[tm][r] += e;
                const u32 bit = (u32)(ws >> ((H * 2 + tn) * 16)) & 1u;
                nacc[tm][r] = fmaf((float)bit, e, nacc[tm][r]);
            }
        }
    }
}

__global__ __launch_bounds__(256, 2)
void cc_main(const u16* __restrict__ xnb, const int* __restrict__ labels,
             const u64* __restrict__ packed,
             float* __restrict__ den, float* __restrict__ num,
             const float* __restrict__ tp, const float* __restrict__ mp) {
    __shared__ u16 As[TILE * LDT];    // 34816 B
    __shared__ u64 Ms[TILE * MSP];    // 17408 B (padded stride)

    const int tid  = threadIdx.x;
    const int lane = tid & 63;
    const int wv   = tid >> 6;
    const int wr   = wv >> 1;
    const int wc   = wv & 1;
    const int m0   = lane & 15;
    const int kq   = lane >> 4;
    const int ibase  = blockIdx.x * TILE;
    const int jsplit = blockIdx.y;
    const int jt0    = jsplit * JQ;

    const float T = tp[0];
    const float M = mp[0];
    const float kA2 = LOG2E / T;
    const float kB2 = -M * LOG2E / T;

    // stage A tile (128 x 128 bf16), each thread 128 B
    {
        const int r = tid >> 1, h = tid & 1;
        const uint4* src = (const uint4*)(xnb + (size_t)(ibase + r) * D + h * 64);
        uint4* dst = (uint4*)(As + r * LDT + h * 64);
        #pragma unroll
        for (int qq = 0; qq < 8; qq++) dst[qq] = src[qq];
    }
    // stage mask words: 128 rows x 16 words (padded row stride 17)
    #pragma unroll
    for (int t = 0; t < 8; t++) {
        const int idx = t * 256 + tid;
        const int row = idx >> 4, h = idx & 15;
        const int lab = labels[ibase + row];
        Ms[row * MSP + h] = packed[(size_t)lab * NW64 + jt0 * 2 + h];
    }
    __syncthreads();

    float dacc[4][4] = {};
    float nacc[4][4] = {};

    const u16* Abase = As + (wr * 64 + m0) * LDT + kq * 8;
    const u16* Blane = xnb + (size_t)(wc * 64 + m0) * D + kq * 8;

    float4v accA[4][2], accB[4][2];
    short8 bc[4][2];

    // prologue: load B(q=0, half0); mfma accA=(0,h0) while reloading bc<-(0,h1)
    {
        const u16* B0 = Blane + (size_t)(jt0 * TILE) * D;
        #pragma unroll
        for (int kk = 0; kk < 4; kk++)
            #pragma unroll
            for (int tn = 0; tn < 2; tn++)
                bc[kk][tn] = *(const short8*)(B0 + tn * (16 * D) + kk * 32);
        mfma_half<true>(accA, Abase, bc, B0 + 32 * D);
    }

    for (int q = 0; q < JQ; q++) {
        const int jt = jt0 + q;
        const int jbase = jt * TILE;
        const u16* Bn = Blane + (size_t)(jbase + TILE) * D;   // next tile base
        const bool diag = (jt == blockIdx.x);

        // mfma accB=(q,h1); reload bc<-(q+1,h0)   [overlaps epi(accA,q,h0)]
        if (q < JQ - 1) mfma_half<true >(accB, Abase, bc, Bn);
        else            mfma_half<false>(accB, Abase, bc, Bn);

        if (diag) epi_half<true , 0>(accA, Ms, dacc, nacc, wr, wc, kq, m0, ibase, jbase, q, kA2, kB2);
        else      epi_half<false, 0>(accA, Ms, dacc, nacc, wr, wc, kq, m0, ibase, jbase, q, kA2, kB2);

        // mfma accA=(q+1,h0); reload bc<-(q+1,h1) [overlaps epi(accB,q,h1)]
        if (q < JQ - 1) mfma_half<true>(accA, Abase, bc, Bn + 32 * D);

        if (diag) epi_half<true , 1>(accB, Ms, dacc, nacc, wr, wc, kq, m0, ibase, jbase, q, kA2, kB2);
        else      epi_half<false, 1>(accB, Ms, dacc, nacc, wr, wc, kq, m0, ibase, jbase, q, kA2, kB2);
    }

    // reduce across the 16 column-lanes, then atomics
    #pragma unroll
    for (int tm = 0; tm < 4; tm++) {
        #pragma unroll
        for (int r = 0; r < 4; r++) {
            float d = dacc[tm][r], n = nacc[tm][r];
            #pragma unroll
            for (int off = 1; off < 16; off <<= 1) {
                d += __shfl_xor(d, off);
                n += __shfl_xor(n, off);
            }
            if (m0 == 0) {
                const int gi = ibase + wr * 64 + tm * 16 + kq * 4 + r;
                atomicAdd(&den[gi], d);
                atomicAdd(&num[gi], n);
            }
        }
    }
}

// ---------------------------------------------------------------------------
// Kernel D: final loss = mean_i -log(T * (p_i + num_i) / (p_i + den_i))
// ---------------------------------------------------------------------------
__global__ void loss_kernel(const float* __restrict__ p, const float* __restrict__ den,
                            const float* __restrict__ num, float* __restrict__ out,
                            const float* __restrict__ tp) {
    __shared__ float red[16];
    const float T = tp[0];
    float s = 0.0f;
    #pragma unroll
    for (int t = 0; t < N / 1024; t++) {
        const int i = t * 1024 + threadIdx.x;
        float pi = p[i];
        s += -__logf(T * (pi + num[i]) / (pi + den[i]));
    }
    #pragma unroll
    for (int off = 32; off; off >>= 1) s += __shfl_xor(s, off);
    const int lane = threadIdx.x & 63, wv = threadIdx.x >> 6;
    if (lane == 0) red[wv] = s;
    __syncthreads();
    if (wv == 0) {
        float t = (lane < 16) ? red[lane] : 0.0f;
        #pragma unroll
        for (int off = 8; off; off >>= 1) t += __shfl_xor(t, off);
        if (lane == 0) out[0] = t / (float)N;
    }
}

// ---------------------------------------------------------------------------
extern "C" void kernel_launch(void* const* d_in, const int* in_sizes, int n_in,
                              void* d_out, int out_size, void* d_ws, size_t ws_size,
                              hipStream_t stream) {
    (void)in_sizes; (void)n_in; (void)out_size; (void)ws_size;
    const float* inst   = (const float*)d_in[0];
    const float* proxy  = (const float*)d_in[1];
    const float* nm     = (const float*)d_in[2];
    const int*   labels = (const int*)d_in[3];
    const float* temp   = (const float*)d_in[4];
    const float* marg   = (const float*)d_in[5];
    float* out = (float*)d_out;

    char* ws = (char*)d_ws;
    u16*   xnb    = (u16*)ws;                         // N*D*2      = 2,097,152 B
    float* p_arr  = (float*)(ws + 2097152);           // N*4        = 32,768 B
    u64*   packed = (u64*)(ws + 2129920);             // C*128*8    = 1,024,000 B
    float* den    = (float*)(ws + 3153920);           // N*4
    float* num    = (float*)(ws + 3186688);           // N*4

    pack_kernel<<<dim3(N / 64, 16), 256, 0, stream>>>(nm, packed);
    norm_kernel<<<N / 4, 256, 0, stream>>>(inst, proxy, xnb, p_arr, den, num, temp, marg);
    cc_main<<<dim3(N / TILE, 8), 256, 0, stream>>>(xnb, labels, packed, den, num, temp, marg);
    loss_kernel<<<1, 1024, 0, stream>>>(p_arr, den, num, out, temp);
}

// Round 17
// 135.604 us; speedup vs baseline: 1.4873x; 1.0138x over previous
//
#include <hip/hip_runtime.h>
#include <hip/hip_bf16.h>

typedef unsigned short u16;
typedef unsigned int   u32;
typedef unsigned long long u64;
typedef __attribute__((ext_vector_type(8))) short short8;   // 8 bf16 (4 VGPRs)
typedef __attribute__((ext_vector_type(4))) float float4v;  // 4 fp32 acc

#define N 8192
#define D 128
#define C 1000
#define TILE 128
#define LDT 136        // padded LDS row stride in bf16
#define NW64 (N / 64)  // 128 packed words per class row
#define JQ 8           // j-tiles per block
#define JW (JQ * 2)    // mask words per row per block
#define LOG2E 1.44269504088896340736f

// ---------------------------------------------------------------------------
// Kernel 1 (prep): fused pack + norm, split by block range (proven in R9).
//   blocks [0, 2048): bit-pack negative_mask [N,C] -> packed[l][w]
//   blocks [2048, 4096): per-row L2 normalize -> bf16, proxy term p_i,
//                        zero den/num.
// ---------------------------------------------------------------------------
__global__ void prep_kernel(const float* __restrict__ nm, u64* __restrict__ packed,
                            const float* __restrict__ x, const float* __restrict__ pr,
                            u16* __restrict__ xnb, float* __restrict__ p_out,
                            float* __restrict__ den, float* __restrict__ num,
                            const float* __restrict__ tp, const float* __restrict__ mp) {
    __shared__ u32 Ls[64 * 65];
    const int bid  = blockIdx.x;
    const int lane = threadIdx.x & 63;
    const int wv   = threadIdx.x >> 6;

    if (bid < 2048) {
        // ---- pack part: 64x64 tile through LDS, column ballots ----
        const int jt = bid & 127;
        const int lt = bid >> 7;
        const int j0 = jt * 64;
        const int l  = lt * 64 + lane;
        const bool lv = l < C;

        #pragma unroll
        for (int rr = 0; rr < 16; rr++) {
            const int r = wv * 16 + rr;
            float v = lv ? nm[(size_t)(j0 + r) * C + l] : 0.0f;
            Ls[r * 65 + lane] = (v > 0.5f) ? 1u : 0u;
        }
        __syncthreads();
        #pragma unroll
        for (int cc = 0; cc < 16; cc++) {
            const int c = wv * 16 + cc;
            u64 m = __ballot(Ls[lane * 65 + c] != 0u);
            if (lane == 0 && (lt * 64 + c) < C)
                packed[(size_t)(lt * 64 + c) * NW64 + jt] = m;
        }
    } else {
        // ---- norm part: one wave per row ----
        const int row = (bid - 2048) * 4 + wv;
        const float2* xr  = (const float2*)(x  + (size_t)row * D);
        const float2* prr = (const float2*)(pr + (size_t)row * D);
        float2 xv = xr[lane];
        float2 pv = prr[lane];

        float sx  = xv.x * xv.x + xv.y * xv.y;
        float sp  = pv.x * pv.x + pv.y * pv.y;
        float sxp = xv.x * pv.x + xv.y * pv.y;
        #pragma unroll
        for (int off = 32; off; off >>= 1) {
            sx  += __shfl_xor(sx,  off);
            sp  += __shfl_xor(sp,  off);
            sxp += __shfl_xor(sxp, off);
        }
        float nx = fmaxf(sqrtf(sx), 1e-8f);
        float np = fmaxf(sqrtf(sp), 1e-8f);
        float inv = 1.0f / nx;

        __hip_bfloat16 b0 = __float2bfloat16(xv.x * inv);
        __hip_bfloat16 b1 = __float2bfloat16(xv.y * inv);
        ((__hip_bfloat162*)xnb)[(size_t)row * 64 + lane] = __halves2bfloat162(b0, b1);

        if (lane == 0) {
            float T = tp[0], M = mp[0];
            p_out[row] = __expf((sxp / (nx * np) - M) / T);
            den[row] = 0.0f;
            num[row] = 0.0f;
        }
    }
}

// ---------------------------------------------------------------------------
// Kernel 2 (cc_main): R11 config VERBATIM (best measured, reproduced twice):
// A+Ms staged once (one barrier), 64x64 wave tile as two 32-col ping-pong
// halves (each epilogue-half overlaps the other half's just-issued MFMA
// block), B depth-1 reload rotation, (256,2) = the only spill-free point.
// grid = (64 i-tiles, 8 j-splits of 8 tiles) = 512 blocks (2/CU).
// ---------------------------------------------------------------------------
template <bool RELOAD>
__device__ __forceinline__ void mfma_half(float4v acc[4][2], const u16* __restrict__ Abase,
                                          short8 bc[4][2], const u16* __restrict__ Bnext) {
    #pragma unroll
    for (int a = 0; a < 4; a++)
        #pragma unroll
        for (int b = 0; b < 2; b++)
            acc[a][b] = (float4v){0.f, 0.f, 0.f, 0.f};
    #pragma unroll
    for (int kk = 0; kk < 4; kk++) {
        short8 a_f[4];
        #pragma unroll
        for (int tm = 0; tm < 4; tm++)
            a_f[tm] = *(const short8*)(Abase + tm * (16 * LDT) + kk * 32);
        #pragma unroll
        for (int tm = 0; tm < 4; tm++)
            #pragma unroll
            for (int tn = 0; tn < 2; tn++)
                acc[tm][tn] = __builtin_amdgcn_mfma_f32_16x16x32_bf16(
                    a_f[tm], bc[kk][tn], acc[tm][tn], 0, 0, 0);
        if (RELOAD) {
            #pragma unroll
            for (int tn = 0; tn < 2; tn++)
                bc[kk][tn] = *(const short8*)(Bnext + tn * (16 * D) + kk * 32);
        }
    }
}

template <bool DIAG, int H>
__device__ __forceinline__ void epi_half(const float4v acc[4][2], const u64* __restrict__ Ms,
                                         float dacc[4][4], float nacc[4][4],
                                         int wr, int wc, int kq, int m0,
                                         int ibase, int jbase, int q,
                                         float kA2, float kB2) {
    #pragma unroll
    for (int tm = 0; tm < 4; tm++) {
        #pragma unroll
        for (int r = 0; r < 4; r++) {
            const int lrow = wr * 64 + tm * 16 + kq * 4 + r;
            const u64 ws = Ms[lrow * JW + q * 2 + wc] >> m0;
            const int gi = ibase + lrow;
            #pragma unroll
            for (int tn = 0; tn < 2; tn++) {
                float e = __builtin_amdgcn_exp2f(fmaf(acc[tm][tn][r], kA2, kB2));
                if (DIAG) {
                    const int gj = jbase + wc * 64 + (H * 2 + tn) * 16 + m0;
                    if (gi == gj) e = 0.0f;
                }
                dacc[tm][r] += e;
                const u32 bit = (u32)(ws >> ((H * 2 + tn) * 16)) & 1u;
                nacc[tm][r] = fmaf((float)bit, e, nacc[tm][r]);
            }
        }
    }
}

__global__ __launch_bounds__(256, 2)
void cc_main(const u16* __restrict__ xnb, const int* __restrict__ labels,
             const u64* __restrict__ packed,
             float* __restrict__ den, float* __restrict__ num,
             const float* __restrict__ tp, const float* __restrict__ mp) {
    __shared__ u16 As[TILE * LDT];    // 34816 B
    __shared__ u64 Ms[TILE * JW];     // 16384 B

    const int tid  = threadIdx.x;
    const int lane = tid & 63;
    const int wv   = tid >> 6;
    const int wr   = wv >> 1;
    const int wc   = wv & 1;
    const int m0   = lane & 15;
    const int kq   = lane >> 4;
    const int ibase  = blockIdx.x * TILE;
    const int jsplit = blockIdx.y;
    const int jt0    = jsplit * JQ;

    const float T = tp[0];
    const float M = mp[0];
    const float kA2 = LOG2E / T;
    const float kB2 = -M * LOG2E / T;

    // stage A tile (128 x 128 bf16), each thread 128 B
    {
        const int r = tid >> 1, h = tid & 1;
        const uint4* src = (const uint4*)(xnb + (size_t)(ibase + r) * D + h * 64);
        uint4* dst = (uint4*)(As + r * LDT + h * 64);
        #pragma unroll
        for (int qq = 0; qq < 8; qq++) dst[qq] = src[qq];
    }
    // stage mask words: 128 rows x 16 words for this j-split
    #pragma unroll
    for (int t = 0; t < 8; t++) {
        const int idx = t * 256 + tid;
        const int row = idx >> 4, h = idx & 15;
        const int lab = labels[ibase + row];
        Ms[idx] = packed[(size_t)lab * NW64 + jt0 * 2 + h];
    }
    __syncthreads();

    float dacc[4][4] = {};
    float nacc[4][4] = {};

    const u16* Abase = As + (wr * 64 + m0) * LDT + kq * 8;
    const u16* Blane = xnb + (size_t)(wc * 64 + m0) * D + kq * 8;

    float4v accA[4][2], accB[4][2];
    short8 bc[4][2];

    // prologue: load B(q=0, half0); mfma accA=(0,h0) while reloading bc<-(0,h1)
    {
        const u16* B0 = Blane + (size_t)(jt0 * TILE) * D;
        #pragma unroll
        for (int kk = 0; kk < 4; kk++)
            #pragma unroll
            for (int tn = 0; tn < 2; tn++)
                bc[kk][tn] = *(const short8*)(B0 + tn * (16 * D) + kk * 32);
        mfma_half<true>(accA, Abase, bc, B0 + 32 * D);
    }

    for (int q = 0; q < JQ; q++) {
        const int jt = jt0 + q;
        const int jbase = jt * TILE;
        const u16* Bn = Blane + (size_t)(jbase + TILE) * D;   // next tile base
        const bool diag = (jt == blockIdx.x);

        // mfma accB=(q,h1); reload bc<-(q+1,h0)   [overlaps epi(accA,q,h0)]
        if (q < JQ - 1) mfma_half<true >(accB, Abase, bc, Bn);
        else            mfma_half<false>(accB, Abase, bc, Bn);

        if (diag) epi_half<true , 0>(accA, Ms, dacc, nacc, wr, wc, kq, m0, ibase, jbase, q, kA2, kB2);
        else      epi_half<false, 0>(accA, Ms, dacc, nacc, wr, wc, kq, m0, ibase, jbase, q, kA2, kB2);

        // mfma accA=(q+1,h0); reload bc<-(q+1,h1) [overlaps epi(accB,q,h1)]
        if (q < JQ - 1) mfma_half<true>(accA, Abase, bc, Bn + 32 * D);

        if (diag) epi_half<true , 1>(accB, Ms, dacc, nacc, wr, wc, kq, m0, ibase, jbase, q, kA2, kB2);
        else      epi_half<false, 1>(accB, Ms, dacc, nacc, wr, wc, kq, m0, ibase, jbase, q, kA2, kB2);
    }

    // reduce across the 16 column-lanes, then atomics
    #pragma unroll
    for (int tm = 0; tm < 4; tm++) {
        #pragma unroll
        for (int r = 0; r < 4; r++) {
            float d = dacc[tm][r], n = nacc[tm][r];
            #pragma unroll
            for (int off = 1; off < 16; off <<= 1) {
                d += __shfl_xor(d, off);
                n += __shfl_xor(n, off);
            }
            if (m0 == 0) {
                const int gi = ibase + wr * 64 + tm * 16 + kq * 4 + r;
                atomicAdd(&den[gi], d);
                atomicAdd(&num[gi], n);
            }
        }
    }
}

// ---------------------------------------------------------------------------
// Kernel 3: final loss = mean_i -log(T * (p_i + num_i) / (p_i + den_i))
// ---------------------------------------------------------------------------
__global__ void loss_kernel(const float* __restrict__ p, const float* __restrict__ den,
                            const float* __restrict__ num, float* __restrict__ out,
                            const float* __restrict__ tp) {
    __shared__ float red[16];
    const float T = tp[0];
    float s = 0.0f;
    #pragma unroll
    for (int t = 0; t < N / 1024; t++) {
        const int i = t * 1024 + threadIdx.x;
        float pi = p[i];
        s += -__logf(T * (pi + num[i]) / (pi + den[i]));
    }
    #pragma unroll
    for (int off = 32; off; off >>= 1) s += __shfl_xor(s, off);
    const int lane = threadIdx.x & 63, wv = threadIdx.x >> 6;
    if (lane == 0) red[wv] = s;
    __syncthreads();
    if (wv == 0) {
        float t = (lane < 16) ? red[lane] : 0.0f;
        #pragma unroll
        for (int off = 8; off; off >>= 1) t += __shfl_xor(t, off);
        if (lane == 0) out[0] = t / (float)N;
    }
}

// ---------------------------------------------------------------------------
extern "C" void kernel_launch(void* const* d_in, const int* in_sizes, int n_in,
                              void* d_out, int out_size, void* d_ws, size_t ws_size,
                              hipStream_t stream) {
    (void)in_sizes; (void)n_in; (void)out_size; (void)ws_size;
    const float* inst   = (const float*)d_in[0];
    const float* proxy  = (const float*)d_in[1];
    const float* nm     = (const float*)d_in[2];
    const int*   labels = (const int*)d_in[3];
    const float* temp   = (const float*)d_in[4];
    const float* marg   = (const float*)d_in[5];
    float* out = (float*)d_out;

    char* ws = (char*)d_ws;
    u16*   xnb    = (u16*)ws;                         // N*D*2      = 2,097,152 B
    float* p_arr  = (float*)(ws + 2097152);           // N*4        = 32,768 B
    u64*   packed = (u64*)(ws + 2129920);             // C*128*8    = 1,024,000 B
    float* den    = (float*)(ws + 3153920);           // N*4
    float* num    = (float*)(ws + 3186688);           // N*4

    prep_kernel<<<4096, 256, 0, stream>>>(nm, packed, inst, proxy, xnb, p_arr,
                                          den, num, temp, marg);
    cc_main<<<dim3(N / TILE, 8), 256, 0, stream>>>(xnb, labels, packed, den, num, temp, marg);
    loss_kernel<<<1, 1024, 0, stream>>>(p_arr, den, num, out, temp);
}